// Round 5
// baseline (131.443 us; speedup 1.0000x reference)
//
#include <hip/hip_runtime.h>
#include <hip/hip_bf16.h>

// ContrastiveLoss: B=8192, D=128, 100 classes.
// loss_i = -log( max(sum_{j!=i, lab_j==lab_i} e^{s_ij},1e-8) / max(sum_{j!=i} e^{s_ij},1e-8) )
// s_ij = clip( f_hat_i . f_hat_j / 0.07, -10, 10 );  out = mean_i loss_i
//
// fb = f_hat * sqrt(log2e/0.07) in bf16 -> MFMA dot yields s/0.07*log2e directly;
// clamp at +-10*log2e (fmed3), single v_exp_f32 (exp2). Diagonal excluded exactly
// via wave-uniform tile check.
//
// R4 change: R3's LDS staging halved simloss (~77->~38us) but 2 blocks/CU x 8
// sequential blocks/CU means ~35% of time is stage+barrier. Double compute per
// staged byte: 64 rows/wave (4 row-tiles, 16 MFMA/jt), grid (32,32) -> per-CU
// staging events halve. Also fold out=0 into normalize_k (kills the memset
// dispatch).

using short8  = __attribute__((ext_vector_type(8))) short;   // 8 bf16 = 4 VGPRs
using floatx4 = __attribute__((ext_vector_type(4))) float;

constexpr int   Bn = 8192;
constexpr int   Dk = 128;
constexpr int   NSLICE = 32;               // j-slices (blockIdx.x)
constexpr float PRESCALE = 4.5398160f;     // sqrt(log2(e)/0.07)
constexpr float CLAMP    = 14.4269504f;    // 10*log2(e)
constexpr float LN2      = 0.69314718056f;

// ---- kernel 1: row L2-normalize, scale, cast to bf16; also zero `out` ----
__global__ __launch_bounds__(256) void normalize_k(
    const float* __restrict__ feat, unsigned short* __restrict__ fb,
    float* __restrict__ out) {
  if (blockIdx.x == 0 && threadIdx.x == 0) *out = 0.f;   // replaces memset dispatch
  const int row  = blockIdx.x * 4 + (threadIdx.x >> 6);
  const int lane = threadIdx.x & 63;
  const float2 v = ((const float2*)(feat + (size_t)row * Dk))[lane];
  float s = v.x * v.x + v.y * v.y;
#pragma unroll
  for (int m = 1; m < 64; m <<= 1) s += __shfl_xor(s, m);
  const float inv = PRESCALE / fmaxf(sqrtf(s), 1e-8f);
  __hip_bfloat16 b0 = __float2bfloat16(v.x * inv);
  __hip_bfloat16 b1 = __float2bfloat16(v.y * inv);
  ushort2 o;
  o.x = __builtin_bit_cast(unsigned short, b0);
  o.y = __builtin_bit_cast(unsigned short, b1);
  ((ushort2*)(fb + (size_t)row * Dk))[lane] = o;
}

// ---- kernel 2: tiled F*F^T with fused exp + masked row-sum --------------
// grid: (32 j-slices, 32 i-blocks). Block = 256 thr = 4 waves.
// Block stages its 256-col B slice (64 KB) in LDS (XOR-16B-chunk swizzle ->
// 2-way bank aliasing = free). Each wave: 64 rows x 256 cols, A frags
// register-resident (16 x short8), 16 col-tiles, 16 MFMA + epilogue per tile.
__global__ __launch_bounds__(256, 2) void simloss_k(
    const unsigned short* __restrict__ fb, const int* __restrict__ labels,
    float* __restrict__ rowpos2, float* __restrict__ rowneg2) {
  __shared__ __align__(16) short Bsh[256 * Dk];   // 65536 B

  const int t     = threadIdx.x;
  const int lane  = t & 63;
  const int wave  = t >> 6;
  const int quad  = lane >> 4;
  const int lr    = lane & 15;
  const int ibase = blockIdx.y * 256 + wave * 64;   // rows [ibase, ibase+64)
  const int jbase = blockIdx.x * 256;               // cols [jbase, jbase+256)

  // ---- A fragments first (latency covered by staging + barrier) ----------
  short8 A[4][4];   // [row-tile][kk]
#pragma unroll
  for (int tt = 0; tt < 4; ++tt) {
    const short* ap = (const short*)fb + (size_t)(ibase + tt * 16 + lr) * Dk + quad * 8;
#pragma unroll
    for (int kk = 0; kk < 4; ++kk) A[tt][kk] = *(const short8*)(ap + kk * 32);
  }

  // ---- stage B slice into LDS, swizzled: chunk c of row r -> c ^ (r&7) ----
  {
    const int chunk = t & 15;        // 16B chunk within a 256B row
    const int r0    = t >> 4;
#pragma unroll
    for (int it = 0; it < 16; ++it) {
      const int row = r0 + it * 16;
      const short8 v = *(const short8*)((const short*)fb +
                          (size_t)(jbase + row) * Dk + chunk * 8);
      *(short8*)(Bsh + row * Dk + ((chunk ^ (row & 7)) * 8)) = v;
    }
  }

  // row labels (accumulator rows: row_in_tile = quad*4 + r)
  int li[4][4];
#pragma unroll
  for (int tt = 0; tt < 4; ++tt)
#pragma unroll
    for (int r = 0; r < 4; ++r)
      li[tt][r] = labels[ibase + tt * 16 + quad * 4 + r];

  // column labels for this lane, one per tile (full unroll keeps in regs)
  int labj[16];
#pragma unroll
  for (int jt = 0; jt < 16; ++jt) labj[jt] = labels[jbase + jt * 16 + lr];

  bool dl[4];
#pragma unroll
  for (int r = 0; r < 4; ++r) dl[r] = (quad * 4 + r) == lr;

  // per-lane swizzled chunk offsets (constant across jt), in shorts
  const int sw = lr & 7;
  const int c0 = ((0 + quad) ^ sw) * 8;
  const int c1 = ((4 + quad) ^ sw) * 8;
  const int c2 = ((8 + quad) ^ sw) * 8;
  const int c3 = ((12 + quad) ^ sw) * 8;

  float pos[4][4] = {};
  float neg[4][4] = {};

  __syncthreads();

#pragma unroll
  for (int jt = 0; jt < 16; ++jt) {
    const short* bp = Bsh + (jt * 16 + lr) * Dk;
    const short8 B0 = *(const short8*)(bp + c0);
    const short8 B1 = *(const short8*)(bp + c1);
    const short8 B2 = *(const short8*)(bp + c2);
    const short8 B3 = *(const short8*)(bp + c3);

    floatx4 acc[4] = {{0.f,0.f,0.f,0.f},{0.f,0.f,0.f,0.f},
                      {0.f,0.f,0.f,0.f},{0.f,0.f,0.f,0.f}};
#pragma unroll
    for (int tt = 0; tt < 4; ++tt)
      acc[tt] = __builtin_amdgcn_mfma_f32_16x16x32_bf16(A[tt][0], B0, acc[tt], 0, 0, 0);
#pragma unroll
    for (int tt = 0; tt < 4; ++tt)
      acc[tt] = __builtin_amdgcn_mfma_f32_16x16x32_bf16(A[tt][1], B1, acc[tt], 0, 0, 0);
#pragma unroll
    for (int tt = 0; tt < 4; ++tt)
      acc[tt] = __builtin_amdgcn_mfma_f32_16x16x32_bf16(A[tt][2], B2, acc[tt], 0, 0, 0);
#pragma unroll
    for (int tt = 0; tt < 4; ++tt)
      acc[tt] = __builtin_amdgcn_mfma_f32_16x16x32_bf16(A[tt][3], B3, acc[tt], 0, 0, 0);

    const int j0 = jbase + jt * 16;
    const int lj = labj[jt];
#pragma unroll
    for (int tt = 0; tt < 4; ++tt) {
      float e[4];
#pragma unroll
      for (int r = 0; r < 4; ++r)
        e[r] = __builtin_amdgcn_exp2f(
            __builtin_amdgcn_fmed3f(acc[tt][r], -CLAMP, CLAMP));
      if (j0 == ibase + tt * 16) {     // wave-uniform: tile on diagonal
#pragma unroll
        for (int r = 0; r < 4; ++r)
          if (dl[r]) e[r] = 0.f;       // exclude i==j exactly
      }
#pragma unroll
      for (int r = 0; r < 4; ++r) {
        neg[tt][r] += e[r];
        pos[tt][r] += (li[tt][r] == lj) ? e[r] : 0.f;
      }
    }
  }

  // reduce across the 16 lanes of a col-group (xor 1,2,4,8 stays in group);
  // unique (slice,row) writer -> plain stores, no atomics, no memset
#pragma unroll
  for (int tt = 0; tt < 4; ++tt)
#pragma unroll
    for (int r = 0; r < 4; ++r) {
      float p = pos[tt][r], n = neg[tt][r];
#pragma unroll
      for (int m = 1; m < 16; m <<= 1) {
        p += __shfl_xor(p, m);
        n += __shfl_xor(n, m);
      }
      if (lr == 0) {
        const int row = ibase + tt * 16 + quad * 4 + r;
        rowpos2[(size_t)blockIdx.x * Bn + row] = p;
        rowneg2[(size_t)blockIdx.x * Bn + row] = n;
      }
    }
}

// ---- kernel 3: sum slice partials, per-row loss, mean (distributed) ------
__global__ __launch_bounds__(256) void finalize_k(
    const float* __restrict__ rowpos2, const float* __restrict__ rowneg2,
    float* __restrict__ out) {
  const int row = blockIdx.x * 256 + threadIdx.x;
  float p = 0.f, n = 0.f;
#pragma unroll
  for (int s = 0; s < NSLICE; ++s) {       // coalesced: consecutive rows adjacent
    p += rowpos2[(size_t)s * Bn + row];
    n += rowneg2[(size_t)s * Bn + row];
  }
  p = fmaxf(p, 1e-8f);
  n = fmaxf(n, 1e-8f);
  float loss = LN2 * (__builtin_amdgcn_logf(n) - __builtin_amdgcn_logf(p));
#pragma unroll
  for (int m = 1; m < 64; m <<= 1) loss += __shfl_xor(loss, m);
  __shared__ float partial[4];
  const int lane = threadIdx.x & 63, w = threadIdx.x >> 6;
  if (lane == 0) partial[w] = loss;
  __syncthreads();
  if (threadIdx.x == 0) {
    const float s = partial[0] + partial[1] + partial[2] + partial[3];
    atomicAdd(out, s * (1.0f / (float)Bn));   // out zeroed by normalize_k
  }
}

extern "C" void kernel_launch(void* const* d_in, const int* in_sizes, int n_in,
                              void* d_out, int out_size, void* d_ws, size_t ws_size,
                              hipStream_t stream) {
  const float* feat   = (const float*)d_in[0];
  const int*   labels = (const int*)d_in[1];
  float* out = (float*)d_out;

  // ws layout: [0, 2MB) bf16 fb[8192][128]; then rowpos2[32][8192], rowneg2[32][8192]
  unsigned short* fb = (unsigned short*)d_ws;
  float* rowpos2 = (float*)((char*)d_ws + (size_t)Bn * Dk * sizeof(unsigned short));
  float* rowneg2 = rowpos2 + (size_t)NSLICE * Bn;

  normalize_k<<<Bn / 4, 256, 0, stream>>>(feat, fb, out);
  dim3 grid(NSLICE, 32);  // x = j-slice, y = i-block (256 rows each)
  simloss_k<<<grid, 256, 0, stream>>>(fb, labels, rowpos2, rowneg2);
  finalize_k<<<Bn / 256, 256, 0, stream>>>(rowpos2, rowneg2, out);
}